// Round 21
// baseline (842.570 us; speedup 1.0000x reference)
//
#include <hip/hip_runtime.h>

#define S_LEN 2048
#define DM 2048
#define NHEAD 16
#define HDIM 128
#define NEXP 8
#define FF 4096
#define EPSV 1e-5f

typedef unsigned short u16;
typedef short bf16x8 __attribute__((ext_vector_type(8)));
typedef float f32x4 __attribute__((ext_vector_type(4)));

__device__ __forceinline__ f32x4 mfma16(bf16x8 a, bf16x8 b, f32x4 c) {
  return __builtin_amdgcn_mfma_f32_16x16x32_bf16(a, b, c, 0, 0, 0);
}

__device__ __forceinline__ float bf2f(u16 u) {
  union { unsigned int i; float f; } v; v.i = ((unsigned int)u) << 16; return v.f;
}
__device__ __forceinline__ u16 f2bf(float f) {
  union { float f; unsigned int i; } v; v.f = f;
  unsigned int u = v.i;
  return (u16)((u + 0x7fffu + ((u >> 16) & 1u)) >> 16);
}

// async global->LDS, 16B per lane; LDS dest = wave-uniform base + lane*16.
__device__ __forceinline__ void gload_lds16(const u16* g, u16* l) {
  __builtin_amdgcn_global_load_lds(
      (const __attribute__((address_space(1))) unsigned int*)(unsigned long long)g,
      (__attribute__((address_space(3))) unsigned int*)(unsigned long long)l, 16, 0, 0);
}

__device__ __forceinline__ float blocksum(float v, float* sh) {
#pragma unroll
  for (int off = 32; off; off >>= 1) v += __shfl_xor(v, off, 64);
  const int w = threadIdx.x >> 6;
  if ((threadIdx.x & 63) == 0) sh[w] = v;
  __syncthreads();
  v = sh[0] + sh[1] + sh[2] + sh[3];
  __syncthreads();
  return v;
}

// ======== weight conversion body: fp32 [K][N] -> bf16 hi/lo transp [N][K] ===
__device__ __forceinline__ void convsplit_body(char* lds, const float* __restrict__ src,
                                               int ld, u16* __restrict__ dhi,
                                               u16* __restrict__ dlo, int nblk, int kblk) {
  float(*tile)[65] = reinterpret_cast<float(*)[65]>(lds);
  const int n0 = nblk * 64, k0 = kblk * 64;
  const int t = threadIdx.x;
  {
    int r = t >> 4, c4 = (t & 15) * 4;
#pragma unroll
    for (int i = 0; i < 4; ++i) {
      float4 v = *reinterpret_cast<const float4*>(src + (size_t)(k0 + r + i * 16) * ld + n0 + c4);
      tile[r + i * 16][c4 + 0] = v.x;
      tile[r + i * 16][c4 + 1] = v.y;
      tile[r + i * 16][c4 + 2] = v.z;
      tile[r + i * 16][c4 + 3] = v.w;
    }
  }
  __syncthreads();
#pragma unroll
  for (int i = 0; i < 2; ++i) {
    int idx = i * 256 + t;
    int n = idx >> 3, kc = (idx & 7) * 8;
    bf16x8 hi, lo;
#pragma unroll
    for (int j = 0; j < 8; ++j) {
      float f = tile[kc + j][n];
      u16 hv = f2bf(f);
      hi[j] = (short)hv;
      lo[j] = (short)f2bf(f - bf2f(hv));
    }
    size_t o = (size_t)(n0 + n) * 2048 + k0 + kc;
    *reinterpret_cast<bf16x8*>(dhi + o) = hi;
    *reinterpret_cast<bf16x8*>(dlo + o) = lo;
  }
}

// ======== expert conv, 2 adjacent n-tiles per block (256 thr) ===============
// 8 outstanding float4 loads per thread before the barrier (2x MLP).
__device__ __forceinline__ void convT_body_x2(char* lds, const float* __restrict__ src,
                                              int R, int C, u16* __restrict__ dst,
                                              int nblk0, int rblk, int e) {
  float(*tile0)[65] = reinterpret_cast<float(*)[65]>(lds);
  float(*tile1)[65] = reinterpret_cast<float(*)[65]>(lds + 16640);
  const int r0 = rblk * 64;
  const size_t bofs = (size_t)e * R * C;
  const int t = threadIdx.x;
  const int r = t >> 4, c4 = (t & 15) * 4;
  const float* bp = src + bofs + (size_t)(r0 + r) * C + nblk0 * 64 + c4;
  float4 v0[4], v1[4];
#pragma unroll
  for (int i = 0; i < 4; ++i) v0[i] = *reinterpret_cast<const float4*>(bp + (size_t)i * 16 * C);
#pragma unroll
  for (int i = 0; i < 4; ++i) v1[i] = *reinterpret_cast<const float4*>(bp + (size_t)i * 16 * C + 64);
#pragma unroll
  for (int i = 0; i < 4; ++i) {
    tile0[r + i * 16][c4 + 0] = v0[i].x; tile0[r + i * 16][c4 + 1] = v0[i].y;
    tile0[r + i * 16][c4 + 2] = v0[i].z; tile0[r + i * 16][c4 + 3] = v0[i].w;
    tile1[r + i * 16][c4 + 0] = v1[i].x; tile1[r + i * 16][c4 + 1] = v1[i].y;
    tile1[r + i * 16][c4 + 2] = v1[i].z; tile1[r + i * 16][c4 + 3] = v1[i].w;
  }
  __syncthreads();
#pragma unroll
  for (int s = 0; s < 2; ++s) {
    float(*tile)[65] = s ? tile1 : tile0;
    const int n0 = (nblk0 + s) * 64;
#pragma unroll
    for (int i = 0; i < 2; ++i) {
      int idx = i * 256 + t;
      int n = idx >> 3, kc = (idx & 7) * 8;
      bf16x8 pk;
#pragma unroll
      for (int j = 0; j < 8; ++j) pk[j] = (short)f2bf(tile[kc + j][n]);
      *reinterpret_cast<bf16x8*>(dst + bofs + (size_t)(n0 + n) * R + r0 + kc) = pk;
    }
  }
}

// ======== expert conv, 2 adjacent n-tiles per block (512 thr) ===============
__device__ __forceinline__ void convT_body512_x2(char* lds, const float* __restrict__ src,
                                                 int R, int C, u16* __restrict__ dst,
                                                 int nblk0, int rblk, int e) {
  float(*tile0)[65] = reinterpret_cast<float(*)[65]>(lds);
  float(*tile1)[65] = reinterpret_cast<float(*)[65]>(lds + 16640);
  const int r0 = rblk * 64;
  const size_t bofs = (size_t)e * R * C;
  const int t = threadIdx.x;
  float4 v0[2], v1[2];
#pragma unroll
  for (int i = 0; i < 2; ++i) {
    int p = i * 512 + t;
    int r = p >> 4, c4 = (p & 15) * 4;
    const float* bp = src + bofs + (size_t)(r0 + r) * C + nblk0 * 64 + c4;
    v0[i] = *reinterpret_cast<const float4*>(bp);
    v1[i] = *reinterpret_cast<const float4*>(bp + 64);
  }
#pragma unroll
  for (int i = 0; i < 2; ++i) {
    int p = i * 512 + t;
    int r = p >> 4, c4 = (p & 15) * 4;
    tile0[r][c4 + 0] = v0[i].x; tile0[r][c4 + 1] = v0[i].y;
    tile0[r][c4 + 2] = v0[i].z; tile0[r][c4 + 3] = v0[i].w;
    tile1[r][c4 + 0] = v1[i].x; tile1[r][c4 + 1] = v1[i].y;
    tile1[r][c4 + 2] = v1[i].z; tile1[r][c4 + 3] = v1[i].w;
  }
  __syncthreads();
  {
    int n = t >> 3, kc = (t & 7) * 8;
    bf16x8 pk0, pk1;
#pragma unroll
    for (int j = 0; j < 8; ++j) {
      pk0[j] = (short)f2bf(tile0[kc + j][n]);
      pk1[j] = (short)f2bf(tile1[kc + j][n]);
    }
    *reinterpret_cast<bf16x8*>(dst + bofs + (size_t)(nblk0 * 64 + n) * R + r0 + kc) = pk0;
    *reinterpret_cast<bf16x8*>(dst + bofs + (size_t)((nblk0 + 1) * 64 + n) * R + r0 + kc) = pk1;
  }
}

// ======== RMSNorm pre body: x -> h1 split hi|lo bf16 [S][4096] ==============
__device__ __forceinline__ void rms_pre_body(char* lds, const float* __restrict__ x,
                                             const float* __restrict__ s,
                                             u16* __restrict__ h1, int row) {
  float* sh = (float*)lds;
  const int t = threadIdx.x;
  const float* xr = x + (size_t)row * DM + t * 8;
  float4 a = *reinterpret_cast<const float4*>(xr);
  float4 b = *reinterpret_cast<const float4*>(xr + 4);
  float v[8] = {a.x, a.y, a.z, a.w, b.x, b.y, b.z, b.w};
  float ss = 0.f;
#pragma unroll
  for (int j = 0; j < 8; ++j) ss += v[j] * v[j];
  float inv = rsqrtf(blocksum(ss, sh) * (1.f / DM) + EPSV);
  const float* sp = s + t * 8;
  bf16x8 hi, lo;
#pragma unroll
  for (int j = 0; j < 8; ++j) {
    float val = v[j] * inv * sp[j];
    u16 hv = f2bf(val);
    hi[j] = (short)hv;
    lo[j] = (short)f2bf(val - bf2f(hv));
  }
  *reinterpret_cast<bf16x8*>(h1 + (size_t)row * 4096 + t * 8) = hi;
  *reinterpret_cast<bf16x8*>(h1 + (size_t)row * 4096 + 2048 + t * 8) = lo;
}

// ======== fat 0: rms_pre (2048) ∪ convsplit wq (1024) ∪ wk (64) ∪ wv (64) ===
__global__ __launch_bounds__(256) void fat_pre(
    const float* __restrict__ x, const float* __restrict__ spre, u16* __restrict__ h1,
    const float* __restrict__ wq, const float* __restrict__ wk, const float* __restrict__ wv,
    u16* __restrict__ BtqHi, u16* __restrict__ BtqLo) {
  __shared__ alignas(16) char lds[16640];
  int bid = blockIdx.x;
  if (bid < 2048) {
    rms_pre_body(lds, x, spre, h1, bid);
  } else if (bid < 3072) {
    int c = bid - 2048;
    convsplit_body(lds, wq, 2048, BtqHi, BtqLo, c & 31, c >> 5);
  } else if (bid < 3136) {
    int c = bid - 3072;
    convsplit_body(lds, wk, 128, BtqHi + (size_t)2048 * 2048, BtqLo + (size_t)2048 * 2048,
                   c & 1, c >> 1);
  } else {
    int c = bid - 3136;
    convsplit_body(lds, wv, 128, BtqHi + (size_t)2176 * 2048, BtqLo + (size_t)2176 * 2048,
                   c & 1, c >> 1);
  }
}

// ======== fused 3-term split GEMM: C = Ahi*Bhi + Alo*Bhi + Ahi*Blo ==========
__device__ __forceinline__ void gemm3_body(
    char* lds, const u16* __restrict__ A, const u16* __restrict__ Bthi,
    const u16* __restrict__ Btlo, void* __restrict__ out,
    int mblk, int nblk, int mode, int ldc, int lo_off) {
  const int m0 = mblk * 128, n0 = nblk * 64;
  const int t = threadIdx.x, lane = t & 63, w = t >> 6;
  const int wm = (w >> 1) * 64, wn = (w & 1) * 32;
  const int l15 = lane & 15, lg = lane >> 4;
  const int wbase = t & ~63;

  u16* Ah = (u16*)lds;             // 128x64
  u16* Al = (u16*)(lds + 16384);   // 128x64
  u16* Bh = (u16*)(lds + 32768);   // 64x64
  u16* Bl = (u16*)(lds + 40960);   // 64x64

  const u16* Abh = A + (size_t)m0 * 4096;
  const u16* Abl = Abh + 2048;
  const u16* Bbh = Bthi + (size_t)n0 * 2048;
  const u16* Bbl = Btlo + (size_t)n0 * 2048;

  f32x4 acc[4][2];
#pragma unroll
  for (int m = 0; m < 4; ++m)
#pragma unroll
    for (int n = 0; n < 2; ++n) acc[m][n] = (f32x4){0.f, 0.f, 0.f, 0.f};

  for (int k0 = 0; k0 < 2048; k0 += 64) {
    __syncthreads();
#pragma unroll
    for (int i = 0; i < 4; ++i) {
      int p = i * 256 + t;
      int row = p >> 3;
      int csrc = (p & 7) ^ (row & 7);
      gload_lds16(Abh + (size_t)row * 4096 + k0 + csrc * 8, Ah + (i * 256 + wbase) * 8);
      gload_lds16(Abl + (size_t)row * 4096 + k0 + csrc * 8, Al + (i * 256 + wbase) * 8);
    }
#pragma unroll
    for (int i = 0; i < 2; ++i) {
      int p = i * 256 + t;
      int row = p >> 3;
      int csrc = (p & 7) ^ (row & 7);
      gload_lds16(Bbh + (size_t)row * 2048 + k0 + csrc * 8, Bh + (i * 256 + wbase) * 8);
      gload_lds16(Bbl + (size_t)row * 2048 + k0 + csrc * 8, Bl + (i * 256 + wbase) * 8);
    }
    __syncthreads();
#pragma unroll
    for (int kk = 0; kk < 2; ++kk) {
      bf16x8 ah[4], al[4], bh[2], bl[2];
#pragma unroll
      for (int m = 0; m < 4; ++m) {
        int row = wm + m * 16 + l15;
        int byte = row * 128 + (((kk * 4 + lg) * 16) ^ ((row & 7) << 4));
        ah[m] = *reinterpret_cast<const bf16x8*>((const char*)Ah + byte);
        al[m] = *reinterpret_cast<const bf16x8*>((const char*)Al + byte);
      }
#pragma unroll
      for (int n = 0; n < 2; ++n) {
        int row = wn + n * 16 + l15;
        int byte = row * 128 + (((kk * 4 + lg) * 16) ^ ((row & 7) << 4));
        bh[n] = *reinterpret_cast<const bf16x8*>((const char*)Bh + byte);
        bl[n] = *reinterpret_cast<const bf16x8*>((const char*)Bl + byte);
      }
      __builtin_amdgcn_s_setprio(1);  // T5: favor MFMA waves vs co-resident conv waves
#pragma unroll
      for (int m = 0; m < 4; ++m)
#pragma unroll
        for (int n = 0; n < 2; ++n) {
          acc[m][n] = mfma16(ah[m], bh[n], acc[m][n]);
          acc[m][n] = mfma16(al[m], bh[n], acc[m][n]);
          acc[m][n] = mfma16(ah[m], bl[n], acc[m][n]);
        }
      __builtin_amdgcn_s_setprio(0);
    }
  }
#pragma unroll
  for (int m = 0; m < 4; ++m)
#pragma unroll
    for (int n = 0; n < 2; ++n)
#pragma unroll
      for (int r = 0; r < 4; ++r) {
        int row = m0 + wm + m * 16 + lg * 4 + r;
        int col = n0 + wn + n * 16 + l15;
        float v = acc[m][n][r];
        if (mode == 1) {
          u16* C = (u16*)out;
          u16 hv = f2bf(v);
          C[(size_t)row * ldc + col] = hv;
          C[(size_t)row * ldc + lo_off + col] = f2bf(v - bf2f(hv));
        } else {
          ((float*)out)[(size_t)row * ldc + col] = v;
        }
      }
}

// ======== fat 1: QKV gemm3 (576) ∪ convT(w1) x2 (8192) ∪ convsplit(wo) (1024)
__global__ __launch_bounds__(256) void fat_qkv_conv(
    const u16* __restrict__ A, const u16* __restrict__ Bthi, const u16* __restrict__ Btlo,
    u16* __restrict__ QKV, const float* __restrict__ w1, u16* __restrict__ w1t,
    const float* __restrict__ wo, u16* __restrict__ BtoHi, u16* __restrict__ BtoLo) {
  __shared__ alignas(16) char lds[49152];
  int bid = blockIdx.x;
  if (bid < 576) {
    gemm3_body(lds, A, Bthi, Btlo, QKV, bid % 16, bid / 16, 1, 4608, 2304);
  } else {
    int cid = bid - 576;
    if (cid < 8192)
      convT_body_x2(lds, w1, 2048, 4096, w1t, (cid & 31) * 2, (cid >> 5) & 31, cid >> 10);
    else {
      cid -= 8192;
      convsplit_body(lds, wo, 2048, BtoHi, BtoLo, cid & 31, cid >> 5);
    }
  }
}

// ======== V transpose: QKV cols 2176..2303 (hi) / 4480..4607 (lo) -> vt =====
__global__ __launch_bounds__(256) void vtrans_kernel(const u16* __restrict__ QKV,
                                                     u16* __restrict__ vt) {
  __shared__ u16 tile[64][65];
  const int s0 = blockIdx.x * 64, c0 = blockIdx.y * 64;
  const int t = threadIdx.x;
#pragma unroll
  for (int i = 0; i < 16; ++i) {
    int idx = i * 256 + t;
    int r = idx >> 6, c = idx & 63;
    int col = c0 + c;
    int src = (col < 128) ? (2176 + col) : (4480 + col - 128);
    tile[r][c] = QKV[(size_t)(s0 + r) * 4608 + src];
  }
  __syncthreads();
#pragma unroll
  for (int i = 0; i < 16; ++i) {
    int idx = i * 256 + t;
    int cc = idx >> 6, ss = idx & 63;
    vt[(size_t)(c0 + cc) * S_LEN + s0 + ss] = tile[ss][cc];
  }
}

// ======== causal MQA flash attention body, KVBLK=32, LDS 47104 B ============
__device__ __forceinline__ void attn_body(char* lds, const u16* __restrict__ QKV,
                                          const u16* __restrict__ vt, u16* __restrict__ Os,
                                          int bx, int h) {
  const int qb = 31 - bx;  // longest blocks first
  const int t = threadIdx.x, w = t >> 6, lane = t & 63;
  const int l15 = lane & 15, lg = lane >> 4;
  const int qr0 = qb * 64 + w * 16;
  const int qrow = qr0 + l15;

  u16* Ks = (u16*)lds;                              // 32*272 u16 = 17408 B
  u16* Vs = (u16*)(lds + 17408);                    // 256*40 u16 = 20480 B
  u16* myP = (u16*)(lds + 37888) + w * (16 * 72);   // 4*1152 u16 = 9216 B

  bf16x8 qf[2][4];
#pragma unroll
  for (int p = 0; p < 2; ++p)
#pragma unroll
    for (int c = 0; c < 4; ++c)
      qf[p][c] = *reinterpret_cast<const bf16x8*>(QKV + (size_t)qrow * 4608 + p * 2304 +
                                                  h * 128 + c * 32 + lg * 8);

  f32x4 o[8];
#pragma unroll
  for (int n = 0; n < 8; ++n) o[n] = (f32x4){0.f, 0.f, 0.f, 0.f};
  f32x4 lracc = (f32x4){0.f, 0.f, 0.f, 0.f};
  bf16x8 onesf;
#pragma unroll
  for (int j = 0; j < 8; ++j) onesf[j] = (short)0x3F80;  // bf16 1.0

  const float scale = 0.08838834764831845f;  // 1/sqrt(128)
  const int kend = qb * 64 + 64;

  for (int j0 = 0; j0 < kend; j0 += 32) {
    __syncthreads();  // previous tile's compute done before overwrite
#pragma unroll
    for (int i = 0; i < 4; ++i) {
      int idx = i * 256 + t;
      int row = idx >> 5, seg = idx & 31;
      int srccol = (seg < 16) ? (2048 + seg * 8) : (4352 + (seg - 16) * 8);
      bf16x8 v = *reinterpret_cast<const bf16x8*>(QKV + (size_t)(j0 + row) * 4608 + srccol);
      *reinterpret_cast<bf16x8*>(&Ks[row * 272 + seg * 8]) = v;
    }
#pragma unroll
    for (int i = 0; i < 4; ++i) {
      int idx = i * 256 + t;
      int row = idx >> 2, seg = idx & 3;
      bf16x8 v = *reinterpret_cast<const bf16x8*>(vt + (size_t)row * S_LEN + j0 + seg * 8);
      *reinterpret_cast<bf16x8*>(&Vs[row * 40 + seg * 8]) = v;
    }
    __syncthreads();

    if (j0 > qr0 + 15) continue;  // wave fully masked (barrier counts match)
    f32x4 sc[2];
#pragma unroll
    for (int half = 0; half < 2; ++half) {
      const int kb = (half * 16 + l15) * 272;
      f32x4 a0 = (f32x4){0.f, 0.f, 0.f, 0.f};
      f32x4 a1 = (f32x4){0.f, 0.f, 0.f, 0.f};
      f32x4 a2 = (f32x4){0.f, 0.f, 0.f, 0.f};
      __builtin_amdgcn_s_setprio(1);  // T5: QK^T MFMA cluster
#pragma unroll
      for (int cc = 0; cc < 4; ++cc) {
        bf16x8 kh = *reinterpret_cast<const bf16x8*>(&Ks[kb + cc * 32 + lg * 8]);
        a0 = mfma16(qf[0][cc], kh, a0);
        a1 = mfma16(qf[1][cc], kh, a1);
      }
#pragma unroll
      for (int cc = 0; cc < 4; ++cc) {
        bf16x8 kl = *reinterpret_cast<const bf16x8*>(&Ks[kb + 128 + cc * 32 + lg * 8]);
        a2 = mfma16(qf[0][cc], kl, a2);
      }
      __builtin_amdgcn_s_setprio(0);
      f32x4 a = (a0 + a1) + a2;
#pragma unroll
      for (int r = 0; r < 4; ++r) {
        int rowg = qr0 + lg * 4 + r;
        int colg = j0 + half * 16 + l15;
        sc[half][r] = (colg <= rowg) ? a[r] * scale : -1e30f;
      }
    }
#pragma unroll
    for (int r = 0; r < 4; ++r) {
      float p0 = __expf(sc[0][r]);
      float p1 = __expf(sc[1][r]);
      int lrow = lg * 4 + r;
      u16 h0 = f2bf(p0), h1v = f2bf(p1);
      myP[lrow * 72 + l15] = h0;
      myP[lrow * 72 + 16 + l15] = h1v;
      myP[lrow * 72 + 32 + l15] = f2bf(p0 - bf2f(h0));
      myP[lrow * 72 + 48 + l15] = f2bf(p1 - bf2f(h1v));
    }
    bf16x8 pfh = *reinterpret_cast<const bf16x8*>(myP + l15 * 72 + lg * 8);
    bf16x8 pfl = *reinterpret_cast<const bf16x8*>(myP + l15 * 72 + 32 + lg * 8);

    lracc = mfma16(pfh, onesf, lracc);
    lracc = mfma16(pfl, onesf, lracc);

    __builtin_amdgcn_s_setprio(1);  // T5: PV MFMA cluster
#pragma unroll
    for (int n = 0; n < 8; ++n) {
      bf16x8 vh = *reinterpret_cast<const bf16x8*>(&Vs[(n * 16 + l15) * 40 + lg * 8]);
      bf16x8 vl = *reinterpret_cast<const bf16x8*>(&Vs[(n * 16 + l15 + 128) * 40 + lg * 8]);
      o[n] = mfma16(pfh, vh, o[n]);
      o[n] = mfma16(pfl, vh, o[n]);
      o[n] = mfma16(pfh, vl, o[n]);
    }
    __builtin_amdgcn_s_setprio(0);
  }
#pragma unroll
  for (int n = 0; n < 8; ++n)
#pragma unroll
    for (int r = 0; r < 4; ++r) {
      int rowg = qr0 + lg * 4 + r;
      float v = o[n][r] / lracc[r];
      u16 hv = f2bf(v);
      Os[(size_t)rowg * 4096 + h * 128 + n * 16 + l15] = hv;
      Os[(size_t)rowg * 4096 + 2048 + h * 128 + n * 16 + l15] = f2bf(v - bf2f(hv));
    }
}

// ======== fat 2: attention (512) ∪ convT(w3) x2 (8192) ======================
__global__ __launch_bounds__(256) void fat_attn_conv(
    const u16* __restrict__ QKV, const u16* __restrict__ vt, u16* __restrict__ Os,
    const float* __restrict__ w3, u16* __restrict__ w3t) {
  __shared__ alignas(16) char lds[47104];
  int bid = blockIdx.x;
  if (bid < 512) {
    attn_body(lds, QKV, vt, Os, bid & 31, bid >> 5);
  } else {
    int cid = bid - 512;
    convT_body_x2(lds, w3, 2048, 4096, w3t, (cid & 31) * 2, (cid >> 5) & 31, cid >> 10);
  }
}

// ======== fat 2b: wo gemm3 (512) ∪ convT(w2 experts 0-3) x2 (4096) ==========
__global__ __launch_bounds__(256) void fat_wo_conv(
    const u16* __restrict__ A, const u16* __restrict__ Bthi, const u16* __restrict__ Btlo,
    float* __restrict__ out, const float* __restrict__ w2, u16* __restrict__ w2t) {
  __shared__ alignas(16) char lds[49152];
  int bid = blockIdx.x;
  if (bid < 512) {
    gemm3_body(lds, A, Bthi, Btlo, out, bid & 15, bid >> 4, 2, 2048, 0);
  } else {
    int cid = bid - 512;
    convT_body_x2(lds, w2, 4096, 2048, w2t, (cid & 15) * 2, (cid >> 4) & 63, cid >> 10);
  }
}

// ======== fused mid: x1 = x + rms(mqa)*s_post; h2b; router top-2 ============
__global__ __launch_bounds__(256) void rms_mid_router(
    const float* __restrict__ x, const float* __restrict__ mqa,
    const float* __restrict__ spost, const float* __restrict__ spre,
    const float* __restrict__ wr, float* __restrict__ x1, u16* __restrict__ h2b,
    float* __restrict__ comb, int* __restrict__ topi, float* __restrict__ topw,
    int* __restrict__ cnt) {
  __shared__ float sh1[4];
  __shared__ float sh2[4];
  __shared__ float red[4][8];
  __shared__ float lgits[8];
  const int row = blockIdx.x, t = threadIdx.x;
  const size_t base = (size_t)row * DM + t * 8;
  float mv[8];
  {
    float4 a0 = *reinterpret_cast<const float4*>(mqa + base);
    float4 b0 = *reinterpret_cast<const float4*>(mqa + base + 4);
    mv[0] = a0.x; mv[1] = a0.y; mv[2] = a0.z; mv[3] = a0.w;
    mv[4] = b0.x; mv[5] = b0.y; mv[6] = b0.z; mv[7] = b0.w;
  }
  float ss1 = 0.f;
#pragma unroll
  for (int j = 0; j < 8; ++j) ss1 += mv[j] * mv[j];
  float inv1 = rsqrtf(blocksum(ss1, sh1) * (1.f / DM) + EPSV);
  float4 xa = *reinterpret_cast<const float4*>(x + base);
  float4 xb = *reinterpret_cast<const float4*>(x + base + 4);
  float xv[8] = {xa.x, xa.y, xa.z, xa.w, xb.x, xb.y, xb.z, xb.w};
  float x1v[8];
  float ss2 = 0.f;
#pragma unroll
  for (int j = 0; j < 8; ++j) {
    x1v[j] = xv[j] + mv[j] * inv1 * spost[t * 8 + j];
    ss2 += x1v[j] * x1v[j];
  }
  float inv2 = rsqrtf(blocksum(ss2, sh2) * (1.f / DM) + EPSV);
  *reinterpret_cast<float4*>(x1 + base) = make_float4(x1v[0], x1v[1], x1v[2], x1v[3]);
  *reinterpret_cast<float4*>(x1 + base + 4) = make_float4(x1v[4], x1v[5], x1v[6], x1v[7]);
  float hv[8];
  bf16x8 hb;
#pragma unroll
  for (int j = 0; j < 8; ++j) {
    hv[j] = x1v[j] * inv2 * spre[t * 8 + j];
    hb[j] = (short)f2bf(hv[j]);
  }
  *reinterpret_cast<bf16x8*>(h2b + base) = hb;

  // ---- router: logits = h2 . wr, top-2, combine weights ----
  float acc[8] = {0.f, 0.f, 0.f, 0.f, 0.f, 0.f, 0.f, 0.f};
  const float* wrow = wr + (size_t)t * 64;
#pragma unroll
  for (int j = 0; j < 8; ++j) {
    const float* wj = wrow + j * 8;
#pragma unroll
    for (int e = 0; e < 8; ++e) acc[e] += hv[j] * wj[e];
  }
#pragma unroll
  for (int off = 32; off; off >>= 1)
#pragma unroll
    for (int e = 0; e < 8; ++e) acc[e] += __shfl_xor(acc[e], off, 64);
  const int w = t >> 6;
  if ((t & 63) == 0) {
#pragma unroll
    for (int e = 0; e < 8; ++e) red[w][e] = acc[e];
  }
  __syncthreads();
  if (t < 8) lgits[t] = red[0][t] + red[1][t] + red[2][t] + red[3][t];
  __syncthreads();
  if (t == 0) {
    float L[8], mx = -1e30f;
#pragma unroll
    for (int e = 0; e < 8; ++e) {
      L[e] = lgits[e];
      mx = fmaxf(mx, L[e]);
    }
    float p[8], s = 0.f;
#pragma unroll
    for (int e = 0; e < 8; ++e) {
      p[e] = expf(L[e] - mx);
      s += p[e];
    }
#pragma unroll
    for (int e = 0; e < 8; ++e) p[e] /= s;
    int e0 = 0;
    for (int e = 1; e < 8; ++e)
      if (p[e] > p[e0]) e0 = e;
    int e1 = (e0 == 0) ? 1 : 0;
    for (int e = 0; e < 8; ++e)
      if (e != e0 && p[e] > p[e1]) e1 = e;
    float ssum = p[e0] + p[e1];
    float w0 = p[e0] / ssum, w1 = p[e1] / ssum;
    for (int e = 0; e < 8; ++e)
      comb[(size_t)row * 8 + e] = (e == e0) ? w0 : ((e == e1) ? w1 : 0.f);
    topi[2 * row] = e0;
    topi[2 * row + 1] = e1;
    topw[2 * row] = w0;
    topw[2 * row + 1] = w1;
    atomicAdd(&cnt[e0], 1);
    atomicAdd(&cnt[e1], 1);
  }
}

// ======== MoE meta ==========================================================
__global__ void zero_meta_kernel(int* __restrict__ cnt) {
  if (threadIdx.x < NEXP) cnt[threadIdx.x] = 0;
}

// builds meta256 (unused) and meta128 (for gemm1 + gemm2)
__global__ void build_meta_kernel(const int* __restrict__ cnt, int* __restrict__ cursor,
                                  int* __restrict__ meta, int* __restrict__ meta128) {
  if (threadIdx.x != 0) return;
  int off = 0, nt = 0, nt2 = 0;
  for (int e = 0; e < NEXP; ++e) {
    int c = cnt[e];
    cursor[e] = off;
    int ntl = (c + 255) >> 8;
    for (int r = 0; r < ntl; ++r) {
      meta[8 + nt] = e;
      meta[64 + nt] = off + r * 256;
      int rem = c - r * 256;
      meta[120 + nt] = rem < 256 ? rem : 256;
      ++nt;
    }
    int ntl2 = (c + 127) >> 7;
    for (int r = 0; r < ntl2; ++r) {
      meta128[8 + nt2] = e;
      meta128[64 + nt2] = off + r * 128;
      int rem = c - r * 128;
      meta128[120 + nt2] = rem < 128 ? rem : 128;
      ++nt2;
    }
    off += c;
  }
  meta[0] = nt;
  meta128[0] = nt2;
}

__global__ void scatter_kernel(const int* __restrict__ topi, int* __restrict__ cursor,
                               int* __restrict__ ptok, int* __restrict__ pos_of) {
  int token = blockIdx.x * 256 + threadIdx.x;
  if (token >= S_LEN) return;
  for (int k = 0; k < 2; ++k) {
    int e = topi[2 * token + k];
    int pos = atomicAdd(&cursor[e], 1);
    ptok[pos] = token;
    pos_of[2 * token + k] = pos;
  }
}

// ======== MoE dual GEMM body, BM=128 BN=64, 512 thr (8 waves 2Mx4N) =========
__device__ __forceinline__ void moe_gemm1_body(
    char* lds, const u16* __restrict__ H2, const u16* __restrict__ W1t,
    const u16* __restrict__ W3t, u16* __restrict__ U, const int* __restrict__ meta,
    const int* __restrict__ ptok, int tile, int n0blk) {
  if (tile >= meta[0]) return;
  u16* As = (u16*)lds;             // 128x64 = 16384 B
  u16* B1s = (u16*)(lds + 16384);  // 64x64  = 8192 B
  u16* B3s = (u16*)(lds + 24576);  // 64x64  = 8192 B
  int* toks = (int*)(lds + 32768); // 512 B
  const int e = meta[8 + tile], row0 = meta[64 + tile], rows = meta[120 + tile];
  const int n0 = n0blk * 64;
  const u16* B1 = W1t + (size_t)e * FF * DM + (size_t)n0 * 2048;
  const u16* B3 = W3t + (size_t)e * FF * DM + (size_t)n0 * 2048;
  const int t = threadIdx.x, lane = t & 63, w = t >> 6;
  const int wm = (w >> 2) * 64, wn = (w & 3) * 16;
  const int l15 = lane & 15, lg = lane >> 4;
  const int wbase = t & ~63;

  if (t < 128) toks[t] = (t < rows) ? ptok[row0 + t] : ptok[row0];
  __syncthreads();

  f32x4 aG[4], aT[4];
#pragma unroll
  for (int m = 0; m < 4; ++m) {
    aG[m] = (f32x4){0.f, 0.f, 0.f, 0.f};
    aT[m] = (f32x4){0.f, 0.f, 0.f, 0.f};
  }

  for (int k0 = 0; k0 < DM; k0 += 64) {
    __syncthreads();
#pragma unroll
    for (int i = 0; i < 2; ++i) {
      int p = i * 512 + t;
      int row = p >> 3;
      int csrc = (p & 7) ^ (row & 7);
      gload_lds16(H2 + (size_t)toks[row] * DM + k0 + csrc * 8, As + (i * 512 + wbase) * 8);
    }
    {
      int row = t >> 3;
      int csrc = (t & 7) ^ (row & 7);
      gload_lds16(B1 + (size_t)row * 2048 + k0 + csrc * 8, B1s + wbase * 8);
      gload_lds16(B3 + (size_t)row * 2048 + k0 + csrc * 8, B3s + wbase * 8);
    }
    __syncthreads();
#pragma unroll
    for (int kk = 0; kk < 2; ++kk) {
      bf16x8 af[4], b1f, b3f;
#pragma unroll
      for (int m = 0; m < 4; ++m) {
        int row = wm + m * 16 + l15;
        int byte = row * 128 + (((kk * 4 + lg) * 16) ^ ((row & 7) << 4));
        af[m] = *reinterpret_cast<const bf16x8*>((const char*)As + byte);
      }
      {
        int row = wn + l15;
        int byte = row * 128 + (((kk * 4 + lg) * 16) ^ ((row & 7) << 4));
        b1f = *reinterpret_cast<const bf16x8*>((const char*)B1s + byte);
        b3f = *reinterpret_cast<const bf16x8*>((const char*)B3s + byte);
      }
      __builtin_amdgcn_s_setprio(1);  // T5: favor MFMA waves vs co-resident conv waves
#pragma unroll
      for (int m = 0; m < 4; ++m) {
        aG[m] = mfma16(af[m], b1f, aG[m]);
        aT[m] = mfma16(af[m], b3f, aT[m]);
      }
      __builtin_amdgcn_s_setprio(0);
    }
  }
#pragma unroll
  for (int m = 0; m < 4; ++m)
#pragma unroll
    for (int r = 0; r < 4; ++r) {
      int lrow = wm + m * 16 + lg * 4 + r;
      if (lrow < rows) {
        float g = aG[m][r], tt = aT[m][r];
        float u = (g / (1.f + __expf(-g))) * tt;
        U[(size_t)(row0 + lrow) * FF + n0 + wn + l15] = f2bf(u);
      }
    }
}

// ======== fat 3: moe_gemm1 BM=128 (2560) ∪ convT(w2 experts 4-7) x2 (4096) ==
__global__ __launch_bounds__(512) void fat_moe1(
    const u16* __restrict__ H2, const u16* __restrict__ W1t, const u16* __restrict__ W3t,
    u16* __restrict__ U, const int* __restrict__ meta128, const int* __restrict__ ptok,
    const float* __restrict__ w2, u16* __restrict__ w2t) {
  __shared__ alignas(16) char lds[33280];
  int bid = blockIdx.x;
  if (bid < 2560) {
    moe_gemm1_body(lds, H2, W1t, W3t, U, meta128, ptok, bid >> 6, bid & 63);
  } else {
    int cid = bid - 2560;
    convT_body512_x2(lds, w2, 4096, 2048, w2t, (cid & 15) * 2, (cid >> 4) & 63,
                     4 + (cid >> 10));
  }
}

// ======== MoE GEMM2, BM=128 BN=128, 512 thr (8 waves 2Mx4N) =================
__global__ __launch_bounds__(512) void moe_gemm2b(
    const u16* __restrict__ U, const u16* __restrict__ W2t, u16* __restrict__ Y,
    const int* __restrict__ meta128) {
  const int tile = blockIdx.x;
  if (tile >= meta128[0]) return;
  const int e = meta128[8 + tile], row0 = meta128[64 + tile], rows = meta128[120 + tile];
  const int n0 = blockIdx.y * 128;
  const u16* Bb = W2t + (size_t)e * DM * FF + (size_t)n0 * 4096;
  const int t = threadIdx.x, lane = t & 63, w = t >> 6;
  const int wm = (w >> 2) * 64, wn = (w & 3) * 32;
  const int l15 = lane & 15, lg = lane >> 4;
  const int wbase = t & ~63;

  __shared__ alignas(16) u16 As[8192];   // 128 x 64
  __shared__ alignas(16) u16 Bs[8192];   // 128 x 64

  f32x4 acc[4][2];
#pragma unroll
  for (int m = 0; m < 4; ++m)
#pragma unroll
    for (int n = 0; n < 2; ++n) acc[m][n] = (f32x4){0.f, 0.f, 0.f, 0.f};

  for (int k0 = 0; k0 < FF; k0 += 64) {
    __syncthreads();
#pragma unroll
    for (int i = 0; i < 2; ++i) {
      int p = i * 512 + t;
      int row = p >> 3;
      int csrc = (p & 7) ^ (row & 7);
      gload_lds16(U + (size_t)(row0 + row) * FF + k0 + csrc * 8, As + (i * 512 + wbase) * 8);
    }
#pragma unroll
    for (int i = 0; i < 2; ++i) {
      int p = i * 512 + t;
      int row = p >> 3;
      int csrc = (p & 7) ^ (row & 7);
      gload_lds16(Bb + (size_t)row * 4096 + k0 + csrc * 8, Bs + (i * 512 + wbase) * 8);
    }
    __syncthreads();
#pragma unroll
    for (int kk = 0; kk < 2; ++kk) {
      bf16x8 af[4], bfr[2];
#pragma unroll
      for (int m = 0; m < 4; ++m) {
        int row = wm + m * 16 + l15;
        int byte = row * 128 + (((kk * 4 + lg) * 16) ^ ((row & 7) << 4));
        af[m] = *reinterpret_cast<const bf16x8*>((const char*)As + byte);
      }
#pragma unroll
      for (int n = 0; n < 2; ++n) {
        int row = wn + n * 16 + l15;
        int byte = row * 128 + (((kk * 4 + lg) * 16) ^ ((row & 7) << 4));
        bfr[n] = *reinterpret_cast<const bf16x8*>((const char*)Bs + byte);
      }
      __builtin_amdgcn_s_setprio(1);  // T5
#pragma unroll
      for (int m = 0; m < 4; ++m)
#pragma unroll
        for (int n = 0; n < 2; ++n) acc[m][n] = mfma16(af[m], bfr[n], acc[m][n]);
      __builtin_amdgcn_s_setprio(0);
    }
  }
#pragma unroll
  for (int m = 0; m < 4; ++m)
#pragma unroll
    for (int n = 0; n < 2; ++n)
#pragma unroll
      for (int r = 0; r < 4; ++r) {
        int lrow = wm + m * 16 + lg * 4 + r;
        if (lrow < rows)
          Y[(size_t)(row0 + lrow) * DM + n0 + wn + n * 16 + l15] = f2bf(acc[m][n][r]);
      }
}

// ======== final =============================================================
__global__ __launch_bounds__(256) void moe_final_kernel(
    const float* __restrict__ x1, const u16* __restrict__ Y,
    const int* __restrict__ pos_of, const float* __restrict__ topw,
    const float* __restrict__ spost, float* __restrict__ xout) {
  __shared__ float sh[4];
  const int row = blockIdx.x, t = threadIdx.x;
  const int p0 = pos_of[2 * row], p1 = pos_of[2 * row + 1];
  const float w0 = topw[2 * row], w1 = topw[2 * row + 1];
  bf16x8 y0 = *reinterpret_cast<const bf16x8*>(Y + (size_t)p0 * DM + t * 8);
  bf16x8 y1 = *reinterpret_cast<const bf16x8*>(Y + (size_t)p1 * DM + t * 8);
  float mv[8];
  float ss = 0.f;
#pragma unroll
  for (int j = 0; j < 8; ++j) {
    mv[j] = w0 * bf2f((u16)y0[j]) + w1 * bf2f((u16)y1[j]);
    ss += mv[j] * mv[j];
  }
  float inv = rsqrtf(blocksum(ss, sh) * (1.f / DM) + EPSV);
  const size_t base = (size_t)row * DM + t * 8;
#pragma unroll
  for (int j = 0; j < 8; ++j)
    xout[base + j] = x1[base + j] + mv[j] * inv * spost[t * 8 + j];
}

// ======== host ==============================================================
extern "C" void kernel_launch(void* const* d_in, const int* in_sizes, int n_in,
                              void* d_out, int out_size, void* d_ws, size_t ws_size,
                              hipStream_t stream) {
  (void)in_sizes; (void)n_in; (void)out_size; (void)ws_size;
  const float* x = (const float*)d_in[0];
  const float* wq = (const float*)d_in[1];
  const float* wk = (const float*)d_in[2];
  const float* wv = (const float*)d_in[3];
  const float* wo = (const float*)d_in[4];
  const float* wrt = (const float*)d_in[5];
  const float* w1 = (const float*)d_in[6];
  const float* w3 = (const float*)d_in[7];
  const float* w2 = (const float*)d_in[8];
  const float* s_pre_mqa = (const float*)d_in[9];
  const float* s_post_mqa = (const float*)d_in[10];
  const float* s_pre_moe = (const float*)d_in[11];
  const float* s_post_moe = (const float*)d_in[12];

  float* xout = (float*)d_out;
  float* out_router = xout + (size_t)S_LEN * DM;

  char* wsp = (char*)d_ws;
  size_t off = 0;
  auto alloc = [&](size_t n) {
    char* p = wsp + off;
    off += (n + 255) & ~(size_t)255;
    return p;
  };
  u16* U = (u16*)alloc((size_t)4096 * FF * 2);
  u16* Y = (u16*)alloc((size_t)4096 * DM * 2);
  float* mqa = (float*)alloc((size_t)S_LEN * DM * 4);
  u16* h1s = (u16*)alloc((size_t)S_LEN * 4096 * 2);
  u16* attn_s = h1s;
  u16* Btq_hi = (u16*)alloc((size_t)2304 * 2048 * 2);
  u16* Btq_lo = (u16*)alloc((size_t)2304 * 2048 * 2);
  u16* Bto_hi = (u16*)alloc((size_t)2048 * 2048 * 2);
  u16* Bto_lo = (u16*)alloc((size_t)2048 * 2048 * 2);
  u16* QKV = (u16*)alloc((size_t)S_LEN * 4608 * 2);
  u16* vt = (u16*)alloc((size_t)256 * S_LEN * 2);
  float* x1 = (float*)alloc((size_t)S_LEN * DM * 4);
  u16* h2b = (u16*)alloc((size_t)S_LEN * DM * 2);
  int* topi = (int*)alloc(4096 * 4);
  float* topw = (float*)alloc(4096 * 4);
  int* pos_of = (int*)alloc(4096 * 4);
  int* ptok = (int*)alloc(4352 * 4);
  int* cnt = (int*)alloc(32 * 4);
  int* cursor = (int*)alloc(32 * 4);
  int* meta = (int*)alloc(256 * 4);
  int* meta128 = (int*)alloc(256 * 4);
  u16* w1t = (u16*)alloc((size_t)NEXP * DM * FF * 2);
  u16* w3t = (u16*)alloc((size_t)NEXP * DM * FF * 2);
  u16* w2t = (u16*)alloc((size_t)NEXP * FF * DM * 2);

  dim3 B256(256);
  dim3 B512(512);

  // pre-phase: rms_pre (2048) ∪ convsplit wq/wk/wv (1152)
  fat_pre<<<dim3(3200), B256, 0, stream>>>(x, s_pre_mqa, h1s, wq, wk, wv, Btq_hi, Btq_lo);
  // QKV gemm3 (576) ∪ convT(w1) x2-tile (8192) ∪ convsplit(wo) (1024)
  fat_qkv_conv<<<dim3(576 + 8192 + 1024), B256, 0, stream>>>(
      h1s, Btq_hi, Btq_lo, QKV, w1, w1t, wo, Bto_hi, Bto_lo);
  vtrans_kernel<<<dim3(32, 4), B256, 0, stream>>>(QKV, vt);
  // attention (512) ∪ convT(w3) x2-tile (8192)
  fat_attn_conv<<<dim3(512 + 8192), B256, 0, stream>>>(QKV, vt, attn_s, w3, w3t);
  // wo gemm3 (512) ∪ convT(w2 experts 0-3) x2-tile (4096)
  fat_wo_conv<<<dim3(512 + 4096), B256, 0, stream>>>(attn_s, Bto_hi, Bto_lo, mqa, w2, w2t);
  zero_meta_kernel<<<dim3(1), dim3(64), 0, stream>>>(cnt);
  rms_mid_router<<<dim3(S_LEN), B256, 0, stream>>>(x, mqa, s_post_mqa, s_pre_moe, wrt,
                                                   x1, h2b, out_router, topi, topw, cnt);
  build_meta_kernel<<<dim3(1), dim3(64), 0, stream>>>(cnt, cursor, meta, meta128);
  scatter_kernel<<<dim3(8), B256, 0, stream>>>(topi, cursor, ptok, pos_of);
  // moe gemm1 BM=128 (2560) ∪ convT(w2 experts 4-7) x2-tile (4096)
  fat_moe1<<<dim3(2560 + 4096), B512, 0, stream>>>(h2b, w1t, w3t, U, meta128, ptok, w2, w2t);
  // moe gemm2 BM=128 BN=128 (40x16)
  moe_gemm2b<<<dim3(40, 16), B512, 0, stream>>>(U, w2t, Y, meta128);
  moe_final_kernel<<<dim3(S_LEN), B256, 0, stream>>>(x1, Y, pos_of, topw, s_post_moe, xout);
}

// Round 22
// 772.548 us; speedup vs baseline: 1.0906x; 1.0906x over previous
//
#include <hip/hip_runtime.h>

#define S_LEN 2048
#define DM 2048
#define NHEAD 16
#define HDIM 128
#define NEXP 8
#define FF 4096
#define EPSV 1e-5f

typedef unsigned short u16;
typedef short bf16x8 __attribute__((ext_vector_type(8)));
typedef float f32x4 __attribute__((ext_vector_type(4)));

__device__ __forceinline__ f32x4 mfma16(bf16x8 a, bf16x8 b, f32x4 c) {
  return __builtin_amdgcn_mfma_f32_16x16x32_bf16(a, b, c, 0, 0, 0);
}

__device__ __forceinline__ float bf2f(u16 u) {
  union { unsigned int i; float f; } v; v.i = ((unsigned int)u) << 16; return v.f;
}
__device__ __forceinline__ u16 f2bf(float f) {
  union { float f; unsigned int i; } v; v.f = f;
  unsigned int u = v.i;
  return (u16)((u + 0x7fffu + ((u >> 16) & 1u)) >> 16);
}

// async global->LDS, 16B per lane; LDS dest = wave-uniform base + lane*16.
__device__ __forceinline__ void gload_lds16(const u16* g, u16* l) {
  __builtin_amdgcn_global_load_lds(
      (const __attribute__((address_space(1))) unsigned int*)(unsigned long long)g,
      (__attribute__((address_space(3))) unsigned int*)(unsigned long long)l, 16, 0, 0);
}

__device__ __forceinline__ float blocksum(float v, float* sh) {
#pragma unroll
  for (int off = 32; off; off >>= 1) v += __shfl_xor(v, off, 64);
  const int w = threadIdx.x >> 6;
  if ((threadIdx.x & 63) == 0) sh[w] = v;
  __syncthreads();
  v = sh[0] + sh[1] + sh[2] + sh[3];
  __syncthreads();
  return v;
}

// ======== weight conversion body: fp32 [K][N] -> bf16 hi/lo transp [N][K] ===
__device__ __forceinline__ void convsplit_body(char* lds, const float* __restrict__ src,
                                               int ld, u16* __restrict__ dhi,
                                               u16* __restrict__ dlo, int nblk, int kblk) {
  float(*tile)[65] = reinterpret_cast<float(*)[65]>(lds);
  const int n0 = nblk * 64, k0 = kblk * 64;
  const int t = threadIdx.x;
  {
    int r = t >> 4, c4 = (t & 15) * 4;
#pragma unroll
    for (int i = 0; i < 4; ++i) {
      float4 v = *reinterpret_cast<const float4*>(src + (size_t)(k0 + r + i * 16) * ld + n0 + c4);
      tile[r + i * 16][c4 + 0] = v.x;
      tile[r + i * 16][c4 + 1] = v.y;
      tile[r + i * 16][c4 + 2] = v.z;
      tile[r + i * 16][c4 + 3] = v.w;
    }
  }
  __syncthreads();
#pragma unroll
  for (int i = 0; i < 2; ++i) {
    int idx = i * 256 + t;
    int n = idx >> 3, kc = (idx & 7) * 8;
    bf16x8 hi, lo;
#pragma unroll
    for (int j = 0; j < 8; ++j) {
      float f = tile[kc + j][n];
      u16 hv = f2bf(f);
      hi[j] = (short)hv;
      lo[j] = (short)f2bf(f - bf2f(hv));
    }
    size_t o = (size_t)(n0 + n) * 2048 + k0 + kc;
    *reinterpret_cast<bf16x8*>(dhi + o) = hi;
    *reinterpret_cast<bf16x8*>(dlo + o) = lo;
  }
}

// ======== expert conv, 2 adjacent n-tiles per block (256 thr) ===============
// 8 outstanding float4 loads per thread before the barrier (2x MLP).
__device__ __forceinline__ void convT_body_x2(char* lds, const float* __restrict__ src,
                                              int R, int C, u16* __restrict__ dst,
                                              int nblk0, int rblk, int e) {
  float(*tile0)[65] = reinterpret_cast<float(*)[65]>(lds);
  float(*tile1)[65] = reinterpret_cast<float(*)[65]>(lds + 16640);
  const int r0 = rblk * 64;
  const size_t bofs = (size_t)e * R * C;
  const int t = threadIdx.x;
  const int r = t >> 4, c4 = (t & 15) * 4;
  const float* bp = src + bofs + (size_t)(r0 + r) * C + nblk0 * 64 + c4;
  float4 v0[4], v1[4];
#pragma unroll
  for (int i = 0; i < 4; ++i) v0[i] = *reinterpret_cast<const float4*>(bp + (size_t)i * 16 * C);
#pragma unroll
  for (int i = 0; i < 4; ++i) v1[i] = *reinterpret_cast<const float4*>(bp + (size_t)i * 16 * C + 64);
#pragma unroll
  for (int i = 0; i < 4; ++i) {
    tile0[r + i * 16][c4 + 0] = v0[i].x; tile0[r + i * 16][c4 + 1] = v0[i].y;
    tile0[r + i * 16][c4 + 2] = v0[i].z; tile0[r + i * 16][c4 + 3] = v0[i].w;
    tile1[r + i * 16][c4 + 0] = v1[i].x; tile1[r + i * 16][c4 + 1] = v1[i].y;
    tile1[r + i * 16][c4 + 2] = v1[i].z; tile1[r + i * 16][c4 + 3] = v1[i].w;
  }
  __syncthreads();
#pragma unroll
  for (int s = 0; s < 2; ++s) {
    float(*tile)[65] = s ? tile1 : tile0;
    const int n0 = (nblk0 + s) * 64;
#pragma unroll
    for (int i = 0; i < 2; ++i) {
      int idx = i * 256 + t;
      int n = idx >> 3, kc = (idx & 7) * 8;
      bf16x8 pk;
#pragma unroll
      for (int j = 0; j < 8; ++j) pk[j] = (short)f2bf(tile[kc + j][n]);
      *reinterpret_cast<bf16x8*>(dst + bofs + (size_t)(n0 + n) * R + r0 + kc) = pk;
    }
  }
}

// ======== expert conv, 2 adjacent n-tiles per block (512 thr) ===============
__device__ __forceinline__ void convT_body512_x2(char* lds, const float* __restrict__ src,
                                                 int R, int C, u16* __restrict__ dst,
                                                 int nblk0, int rblk, int e) {
  float(*tile0)[65] = reinterpret_cast<float(*)[65]>(lds);
  float(*tile1)[65] = reinterpret_cast<float(*)[65]>(lds + 16640);
  const int r0 = rblk * 64;
  const size_t bofs = (size_t)e * R * C;
  const int t = threadIdx.x;
  float4 v0[2], v1[2];
#pragma unroll
  for (int i = 0; i < 2; ++i) {
    int p = i * 512 + t;
    int r = p >> 4, c4 = (p & 15) * 4;
    const float* bp = src + bofs + (size_t)(r0 + r) * C + nblk0 * 64 + c4;
    v0[i] = *reinterpret_cast<const float4*>(bp);
    v1[i] = *reinterpret_cast<const float4*>(bp + 64);
  }
#pragma unroll
  for (int i = 0; i < 2; ++i) {
    int p = i * 512 + t;
    int r = p >> 4, c4 = (p & 15) * 4;
    tile0[r][c4 + 0] = v0[i].x; tile0[r][c4 + 1] = v0[i].y;
    tile0[r][c4 + 2] = v0[i].z; tile0[r][c4 + 3] = v0[i].w;
    tile1[r][c4 + 0] = v1[i].x; tile1[r][c4 + 1] = v1[i].y;
    tile1[r][c4 + 2] = v1[i].z; tile1[r][c4 + 3] = v1[i].w;
  }
  __syncthreads();
  {
    int n = t >> 3, kc = (t & 7) * 8;
    bf16x8 pk0, pk1;
#pragma unroll
    for (int j = 0; j < 8; ++j) {
      pk0[j] = (short)f2bf(tile0[kc + j][n]);
      pk1[j] = (short)f2bf(tile1[kc + j][n]);
    }
    *reinterpret_cast<bf16x8*>(dst + bofs + (size_t)(nblk0 * 64 + n) * R + r0 + kc) = pk0;
    *reinterpret_cast<bf16x8*>(dst + bofs + (size_t)((nblk0 + 1) * 64 + n) * R + r0 + kc) = pk1;
  }
}

// ======== RMSNorm pre body: x -> h1 split hi|lo bf16 [S][4096] ==============
__device__ __forceinline__ void rms_pre_body(char* lds, const float* __restrict__ x,
                                             const float* __restrict__ s,
                                             u16* __restrict__ h1, int row) {
  float* sh = (float*)lds;
  const int t = threadIdx.x;
  const float* xr = x + (size_t)row * DM + t * 8;
  float4 a = *reinterpret_cast<const float4*>(xr);
  float4 b = *reinterpret_cast<const float4*>(xr + 4);
  float v[8] = {a.x, a.y, a.z, a.w, b.x, b.y, b.z, b.w};
  float ss = 0.f;
#pragma unroll
  for (int j = 0; j < 8; ++j) ss += v[j] * v[j];
  float inv = rsqrtf(blocksum(ss, sh) * (1.f / DM) + EPSV);
  const float* sp = s + t * 8;
  bf16x8 hi, lo;
#pragma unroll
  for (int j = 0; j < 8; ++j) {
    float val = v[j] * inv * sp[j];
    u16 hv = f2bf(val);
    hi[j] = (short)hv;
    lo[j] = (short)f2bf(val - bf2f(hv));
  }
  *reinterpret_cast<bf16x8*>(h1 + (size_t)row * 4096 + t * 8) = hi;
  *reinterpret_cast<bf16x8*>(h1 + (size_t)row * 4096 + 2048 + t * 8) = lo;
}

// ======== fat 0: rms_pre (2048) ∪ convsplit wq (1024) ∪ wk (64) ∪ wv (64) ===
__global__ __launch_bounds__(256) void fat_pre(
    const float* __restrict__ x, const float* __restrict__ spre, u16* __restrict__ h1,
    const float* __restrict__ wq, const float* __restrict__ wk, const float* __restrict__ wv,
    u16* __restrict__ BtqHi, u16* __restrict__ BtqLo) {
  __shared__ alignas(16) char lds[16640];
  int bid = blockIdx.x;
  if (bid < 2048) {
    rms_pre_body(lds, x, spre, h1, bid);
  } else if (bid < 3072) {
    int c = bid - 2048;
    convsplit_body(lds, wq, 2048, BtqHi, BtqLo, c & 31, c >> 5);
  } else if (bid < 3136) {
    int c = bid - 3072;
    convsplit_body(lds, wk, 128, BtqHi + (size_t)2048 * 2048, BtqLo + (size_t)2048 * 2048,
                   c & 1, c >> 1);
  } else {
    int c = bid - 3136;
    convsplit_body(lds, wv, 128, BtqHi + (size_t)2176 * 2048, BtqLo + (size_t)2176 * 2048,
                   c & 1, c >> 1);
  }
}

// ======== fused 3-term split GEMM: C = Ahi*Bhi + Alo*Bhi + Ahi*Blo ==========
__device__ __forceinline__ void gemm3_body(
    char* lds, const u16* __restrict__ A, const u16* __restrict__ Bthi,
    const u16* __restrict__ Btlo, void* __restrict__ out,
    int mblk, int nblk, int mode, int ldc, int lo_off) {
  const int m0 = mblk * 128, n0 = nblk * 64;
  const int t = threadIdx.x, lane = t & 63, w = t >> 6;
  const int wm = (w >> 1) * 64, wn = (w & 1) * 32;
  const int l15 = lane & 15, lg = lane >> 4;
  const int wbase = t & ~63;

  u16* Ah = (u16*)lds;             // 128x64
  u16* Al = (u16*)(lds + 16384);   // 128x64
  u16* Bh = (u16*)(lds + 32768);   // 64x64
  u16* Bl = (u16*)(lds + 40960);   // 64x64

  const u16* Abh = A + (size_t)m0 * 4096;
  const u16* Abl = Abh + 2048;
  const u16* Bbh = Bthi + (size_t)n0 * 2048;
  const u16* Bbl = Btlo + (size_t)n0 * 2048;

  f32x4 acc[4][2];
#pragma unroll
  for (int m = 0; m < 4; ++m)
#pragma unroll
    for (int n = 0; n < 2; ++n) acc[m][n] = (f32x4){0.f, 0.f, 0.f, 0.f};

  for (int k0 = 0; k0 < 2048; k0 += 64) {
    __syncthreads();
#pragma unroll
    for (int i = 0; i < 4; ++i) {
      int p = i * 256 + t;
      int row = p >> 3;
      int csrc = (p & 7) ^ (row & 7);
      gload_lds16(Abh + (size_t)row * 4096 + k0 + csrc * 8, Ah + (i * 256 + wbase) * 8);
      gload_lds16(Abl + (size_t)row * 4096 + k0 + csrc * 8, Al + (i * 256 + wbase) * 8);
    }
#pragma unroll
    for (int i = 0; i < 2; ++i) {
      int p = i * 256 + t;
      int row = p >> 3;
      int csrc = (p & 7) ^ (row & 7);
      gload_lds16(Bbh + (size_t)row * 2048 + k0 + csrc * 8, Bh + (i * 256 + wbase) * 8);
      gload_lds16(Bbl + (size_t)row * 2048 + k0 + csrc * 8, Bl + (i * 256 + wbase) * 8);
    }
    __syncthreads();
#pragma unroll
    for (int kk = 0; kk < 2; ++kk) {
      bf16x8 ah[4], al[4], bh[2], bl[2];
#pragma unroll
      for (int m = 0; m < 4; ++m) {
        int row = wm + m * 16 + l15;
        int byte = row * 128 + (((kk * 4 + lg) * 16) ^ ((row & 7) << 4));
        ah[m] = *reinterpret_cast<const bf16x8*>((const char*)Ah + byte);
        al[m] = *reinterpret_cast<const bf16x8*>((const char*)Al + byte);
      }
#pragma unroll
      for (int n = 0; n < 2; ++n) {
        int row = wn + n * 16 + l15;
        int byte = row * 128 + (((kk * 4 + lg) * 16) ^ ((row & 7) << 4));
        bh[n] = *reinterpret_cast<const bf16x8*>((const char*)Bh + byte);
        bl[n] = *reinterpret_cast<const bf16x8*>((const char*)Bl + byte);
      }
#pragma unroll
      for (int m = 0; m < 4; ++m)
#pragma unroll
        for (int n = 0; n < 2; ++n) {
          acc[m][n] = mfma16(ah[m], bh[n], acc[m][n]);
          acc[m][n] = mfma16(al[m], bh[n], acc[m][n]);
          acc[m][n] = mfma16(ah[m], bl[n], acc[m][n]);
        }
    }
  }
#pragma unroll
  for (int m = 0; m < 4; ++m)
#pragma unroll
    for (int n = 0; n < 2; ++n)
#pragma unroll
      for (int r = 0; r < 4; ++r) {
        int row = m0 + wm + m * 16 + lg * 4 + r;
        int col = n0 + wn + n * 16 + l15;
        float v = acc[m][n][r];
        if (mode == 1) {
          u16* C = (u16*)out;
          u16 hv = f2bf(v);
          C[(size_t)row * ldc + col] = hv;
          C[(size_t)row * ldc + lo_off + col] = f2bf(v - bf2f(hv));
        } else {
          ((float*)out)[(size_t)row * ldc + col] = v;
        }
      }
}

// ======== fat 1: QKV gemm3 (576) ∪ convT(w1) x2 (8192) ∪ convsplit(wo) (1024)
__global__ __launch_bounds__(256) void fat_qkv_conv(
    const u16* __restrict__ A, const u16* __restrict__ Bthi, const u16* __restrict__ Btlo,
    u16* __restrict__ QKV, const float* __restrict__ w1, u16* __restrict__ w1t,
    const float* __restrict__ wo, u16* __restrict__ BtoHi, u16* __restrict__ BtoLo) {
  __shared__ alignas(16) char lds[49152];
  int bid = blockIdx.x;
  if (bid < 576) {
    gemm3_body(lds, A, Bthi, Btlo, QKV, bid % 16, bid / 16, 1, 4608, 2304);
  } else {
    int cid = bid - 576;
    if (cid < 8192)
      convT_body_x2(lds, w1, 2048, 4096, w1t, (cid & 31) * 2, (cid >> 5) & 31, cid >> 10);
    else {
      cid -= 8192;
      convsplit_body(lds, wo, 2048, BtoHi, BtoLo, cid & 31, cid >> 5);
    }
  }
}

// ======== V transpose: QKV cols 2176..2303 (hi) / 4480..4607 (lo) -> vt =====
__global__ __launch_bounds__(256) void vtrans_kernel(const u16* __restrict__ QKV,
                                                     u16* __restrict__ vt) {
  __shared__ u16 tile[64][65];
  const int s0 = blockIdx.x * 64, c0 = blockIdx.y * 64;
  const int t = threadIdx.x;
#pragma unroll
  for (int i = 0; i < 16; ++i) {
    int idx = i * 256 + t;
    int r = idx >> 6, c = idx & 63;
    int col = c0 + c;
    int src = (col < 128) ? (2176 + col) : (4480 + col - 128);
    tile[r][c] = QKV[(size_t)(s0 + r) * 4608 + src];
  }
  __syncthreads();
#pragma unroll
  for (int i = 0; i < 16; ++i) {
    int idx = i * 256 + t;
    int cc = idx >> 6, ss = idx & 63;
    vt[(size_t)(c0 + cc) * S_LEN + s0 + ss] = tile[ss][cc];
  }
}

// ======== causal MQA flash attention body, KVBLK=32, LDS 47104 B ============
__device__ __forceinline__ void attn_body(char* lds, const u16* __restrict__ QKV,
                                          const u16* __restrict__ vt, u16* __restrict__ Os,
                                          int bx, int h) {
  const int qb = 31 - bx;  // longest blocks first
  const int t = threadIdx.x, w = t >> 6, lane = t & 63;
  const int l15 = lane & 15, lg = lane >> 4;
  const int qr0 = qb * 64 + w * 16;
  const int qrow = qr0 + l15;

  u16* Ks = (u16*)lds;                              // 32*272 u16 = 17408 B
  u16* Vs = (u16*)(lds + 17408);                    // 256*40 u16 = 20480 B
  u16* myP = (u16*)(lds + 37888) + w * (16 * 72);   // 4*1152 u16 = 9216 B

  bf16x8 qf[2][4];
#pragma unroll
  for (int p = 0; p < 2; ++p)
#pragma unroll
    for (int c = 0; c < 4; ++c)
      qf[p][c] = *reinterpret_cast<const bf16x8*>(QKV + (size_t)qrow * 4608 + p * 2304 +
                                                  h * 128 + c * 32 + lg * 8);

  f32x4 o[8];
#pragma unroll
  for (int n = 0; n < 8; ++n) o[n] = (f32x4){0.f, 0.f, 0.f, 0.f};
  f32x4 lracc = (f32x4){0.f, 0.f, 0.f, 0.f};
  bf16x8 onesf;
#pragma unroll
  for (int j = 0; j < 8; ++j) onesf[j] = (short)0x3F80;  // bf16 1.0

  const float scale = 0.08838834764831845f;  // 1/sqrt(128)
  const int kend = qb * 64 + 64;

  for (int j0 = 0; j0 < kend; j0 += 32) {
    __syncthreads();  // previous tile's compute done before overwrite
#pragma unroll
    for (int i = 0; i < 4; ++i) {
      int idx = i * 256 + t;
      int row = idx >> 5, seg = idx & 31;
      int srccol = (seg < 16) ? (2048 + seg * 8) : (4352 + (seg - 16) * 8);
      bf16x8 v = *reinterpret_cast<const bf16x8*>(QKV + (size_t)(j0 + row) * 4608 + srccol);
      *reinterpret_cast<bf16x8*>(&Ks[row * 272 + seg * 8]) = v;
    }
#pragma unroll
    for (int i = 0; i < 4; ++i) {
      int idx = i * 256 + t;
      int row = idx >> 2, seg = idx & 3;
      bf16x8 v = *reinterpret_cast<const bf16x8*>(vt + (size_t)row * S_LEN + j0 + seg * 8);
      *reinterpret_cast<bf16x8*>(&Vs[row * 40 + seg * 8]) = v;
    }
    __syncthreads();

    if (j0 > qr0 + 15) continue;  // wave fully masked (barrier counts match)
    f32x4 sc[2];
#pragma unroll
    for (int half = 0; half < 2; ++half) {
      const int kb = (half * 16 + l15) * 272;
      f32x4 a0 = (f32x4){0.f, 0.f, 0.f, 0.f};
      f32x4 a1 = (f32x4){0.f, 0.f, 0.f, 0.f};
      f32x4 a2 = (f32x4){0.f, 0.f, 0.f, 0.f};
#pragma unroll
      for (int cc = 0; cc < 4; ++cc) {
        bf16x8 kh = *reinterpret_cast<const bf16x8*>(&Ks[kb + cc * 32 + lg * 8]);
        a0 = mfma16(qf[0][cc], kh, a0);
        a1 = mfma16(qf[1][cc], kh, a1);
      }
#pragma unroll
      for (int cc = 0; cc < 4; ++cc) {
        bf16x8 kl = *reinterpret_cast<const bf16x8*>(&Ks[kb + 128 + cc * 32 + lg * 8]);
        a2 = mfma16(qf[0][cc], kl, a2);
      }
      f32x4 a = (a0 + a1) + a2;
#pragma unroll
      for (int r = 0; r < 4; ++r) {
        int rowg = qr0 + lg * 4 + r;
        int colg = j0 + half * 16 + l15;
        sc[half][r] = (colg <= rowg) ? a[r] * scale : -1e30f;
      }
    }
#pragma unroll
    for (int r = 0; r < 4; ++r) {
      float p0 = __expf(sc[0][r]);
      float p1 = __expf(sc[1][r]);
      int lrow = lg * 4 + r;
      u16 h0 = f2bf(p0), h1v = f2bf(p1);
      myP[lrow * 72 + l15] = h0;
      myP[lrow * 72 + 16 + l15] = h1v;
      myP[lrow * 72 + 32 + l15] = f2bf(p0 - bf2f(h0));
      myP[lrow * 72 + 48 + l15] = f2bf(p1 - bf2f(h1v));
    }
    bf16x8 pfh = *reinterpret_cast<const bf16x8*>(myP + l15 * 72 + lg * 8);
    bf16x8 pfl = *reinterpret_cast<const bf16x8*>(myP + l15 * 72 + 32 + lg * 8);

    lracc = mfma16(pfh, onesf, lracc);
    lracc = mfma16(pfl, onesf, lracc);

#pragma unroll
    for (int n = 0; n < 8; ++n) {
      bf16x8 vh = *reinterpret_cast<const bf16x8*>(&Vs[(n * 16 + l15) * 40 + lg * 8]);
      bf16x8 vl = *reinterpret_cast<const bf16x8*>(&Vs[(n * 16 + l15 + 128) * 40 + lg * 8]);
      o[n] = mfma16(pfh, vh, o[n]);
      o[n] = mfma16(pfl, vh, o[n]);
      o[n] = mfma16(pfh, vl, o[n]);
    }
  }
#pragma unroll
  for (int n = 0; n < 8; ++n)
#pragma unroll
    for (int r = 0; r < 4; ++r) {
      int rowg = qr0 + lg * 4 + r;
      float v = o[n][r] / lracc[r];
      u16 hv = f2bf(v);
      Os[(size_t)rowg * 4096 + h * 128 + n * 16 + l15] = hv;
      Os[(size_t)rowg * 4096 + 2048 + h * 128 + n * 16 + l15] = f2bf(v - bf2f(hv));
    }
}

// ======== fat 2: attention (512) ∪ convT(w3) x2 (8192) ======================
__global__ __launch_bounds__(256) void fat_attn_conv(
    const u16* __restrict__ QKV, const u16* __restrict__ vt, u16* __restrict__ Os,
    const float* __restrict__ w3, u16* __restrict__ w3t) {
  __shared__ alignas(16) char lds[47104];
  int bid = blockIdx.x;
  if (bid < 512) {
    attn_body(lds, QKV, vt, Os, bid & 31, bid >> 5);
  } else {
    int cid = bid - 512;
    convT_body_x2(lds, w3, 2048, 4096, w3t, (cid & 31) * 2, (cid >> 5) & 31, cid >> 10);
  }
}

// ======== fat 2b: wo gemm3 (512) ∪ convT(w2 experts 0-3) x2 (4096) ==========
__global__ __launch_bounds__(256) void fat_wo_conv(
    const u16* __restrict__ A, const u16* __restrict__ Bthi, const u16* __restrict__ Btlo,
    float* __restrict__ out, const float* __restrict__ w2, u16* __restrict__ w2t) {
  __shared__ alignas(16) char lds[49152];
  int bid = blockIdx.x;
  if (bid < 512) {
    gemm3_body(lds, A, Bthi, Btlo, out, bid & 15, bid >> 4, 2, 2048, 0);
  } else {
    int cid = bid - 512;
    convT_body_x2(lds, w2, 4096, 2048, w2t, (cid & 15) * 2, (cid >> 4) & 63, cid >> 10);
  }
}

// ======== fused mid: x1 = x + rms(mqa)*s_post; h2b; router top-2 ============
__global__ __launch_bounds__(256) void rms_mid_router(
    const float* __restrict__ x, const float* __restrict__ mqa,
    const float* __restrict__ spost, const float* __restrict__ spre,
    const float* __restrict__ wr, float* __restrict__ x1, u16* __restrict__ h2b,
    float* __restrict__ comb, int* __restrict__ topi, float* __restrict__ topw,
    int* __restrict__ cnt) {
  __shared__ float sh1[4];
  __shared__ float sh2[4];
  __shared__ float red[4][8];
  __shared__ float lgits[8];
  const int row = blockIdx.x, t = threadIdx.x;
  const size_t base = (size_t)row * DM + t * 8;
  float mv[8];
  {
    float4 a0 = *reinterpret_cast<const float4*>(mqa + base);
    float4 b0 = *reinterpret_cast<const float4*>(mqa + base + 4);
    mv[0] = a0.x; mv[1] = a0.y; mv[2] = a0.z; mv[3] = a0.w;
    mv[4] = b0.x; mv[5] = b0.y; mv[6] = b0.z; mv[7] = b0.w;
  }
  float ss1 = 0.f;
#pragma unroll
  for (int j = 0; j < 8; ++j) ss1 += mv[j] * mv[j];
  float inv1 = rsqrtf(blocksum(ss1, sh1) * (1.f / DM) + EPSV);
  float4 xa = *reinterpret_cast<const float4*>(x + base);
  float4 xb = *reinterpret_cast<const float4*>(x + base + 4);
  float xv[8] = {xa.x, xa.y, xa.z, xa.w, xb.x, xb.y, xb.z, xb.w};
  float x1v[8];
  float ss2 = 0.f;
#pragma unroll
  for (int j = 0; j < 8; ++j) {
    x1v[j] = xv[j] + mv[j] * inv1 * spost[t * 8 + j];
    ss2 += x1v[j] * x1v[j];
  }
  float inv2 = rsqrtf(blocksum(ss2, sh2) * (1.f / DM) + EPSV);
  *reinterpret_cast<float4*>(x1 + base) = make_float4(x1v[0], x1v[1], x1v[2], x1v[3]);
  *reinterpret_cast<float4*>(x1 + base + 4) = make_float4(x1v[4], x1v[5], x1v[6], x1v[7]);
  float hv[8];
  bf16x8 hb;
#pragma unroll
  for (int j = 0; j < 8; ++j) {
    hv[j] = x1v[j] * inv2 * spre[t * 8 + j];
    hb[j] = (short)f2bf(hv[j]);
  }
  *reinterpret_cast<bf16x8*>(h2b + base) = hb;

  // ---- router: logits = h2 . wr, top-2, combine weights ----
  float acc[8] = {0.f, 0.f, 0.f, 0.f, 0.f, 0.f, 0.f, 0.f};
  const float* wrow = wr + (size_t)t * 64;
#pragma unroll
  for (int j = 0; j < 8; ++j) {
    const float* wj = wrow + j * 8;
#pragma unroll
    for (int e = 0; e < 8; ++e) acc[e] += hv[j] * wj[e];
  }
#pragma unroll
  for (int off = 32; off; off >>= 1)
#pragma unroll
    for (int e = 0; e < 8; ++e) acc[e] += __shfl_xor(acc[e], off, 64);
  const int w = t >> 6;
  if ((t & 63) == 0) {
#pragma unroll
    for (int e = 0; e < 8; ++e) red[w][e] = acc[e];
  }
  __syncthreads();
  if (t < 8) lgits[t] = red[0][t] + red[1][t] + red[2][t] + red[3][t];
  __syncthreads();
  if (t == 0) {
    float L[8], mx = -1e30f;
#pragma unroll
    for (int e = 0; e < 8; ++e) {
      L[e] = lgits[e];
      mx = fmaxf(mx, L[e]);
    }
    float p[8], s = 0.f;
#pragma unroll
    for (int e = 0; e < 8; ++e) {
      p[e] = expf(L[e] - mx);
      s += p[e];
    }
#pragma unroll
    for (int e = 0; e < 8; ++e) p[e] /= s;
    int e0 = 0;
    for (int e = 1; e < 8; ++e)
      if (p[e] > p[e0]) e0 = e;
    int e1 = (e0 == 0) ? 1 : 0;
    for (int e = 0; e < 8; ++e)
      if (e != e0 && p[e] > p[e1]) e1 = e;
    float ssum = p[e0] + p[e1];
    float w0 = p[e0] / ssum, w1 = p[e1] / ssum;
    for (int e = 0; e < 8; ++e)
      comb[(size_t)row * 8 + e] = (e == e0) ? w0 : ((e == e1) ? w1 : 0.f);
    topi[2 * row] = e0;
    topi[2 * row + 1] = e1;
    topw[2 * row] = w0;
    topw[2 * row + 1] = w1;
    atomicAdd(&cnt[e0], 1);
    atomicAdd(&cnt[e1], 1);
  }
}

// ======== MoE meta ==========================================================
__global__ void zero_meta_kernel(int* __restrict__ cnt) {
  if (threadIdx.x < NEXP) cnt[threadIdx.x] = 0;
}

// builds meta256 (unused) and meta128 (for gemm1 + gemm2)
__global__ void build_meta_kernel(const int* __restrict__ cnt, int* __restrict__ cursor,
                                  int* __restrict__ meta, int* __restrict__ meta128) {
  if (threadIdx.x != 0) return;
  int off = 0, nt = 0, nt2 = 0;
  for (int e = 0; e < NEXP; ++e) {
    int c = cnt[e];
    cursor[e] = off;
    int ntl = (c + 255) >> 8;
    for (int r = 0; r < ntl; ++r) {
      meta[8 + nt] = e;
      meta[64 + nt] = off + r * 256;
      int rem = c - r * 256;
      meta[120 + nt] = rem < 256 ? rem : 256;
      ++nt;
    }
    int ntl2 = (c + 127) >> 7;
    for (int r = 0; r < ntl2; ++r) {
      meta128[8 + nt2] = e;
      meta128[64 + nt2] = off + r * 128;
      int rem = c - r * 128;
      meta128[120 + nt2] = rem < 128 ? rem : 128;
      ++nt2;
    }
    off += c;
  }
  meta[0] = nt;
  meta128[0] = nt2;
}

__global__ void scatter_kernel(const int* __restrict__ topi, int* __restrict__ cursor,
                               int* __restrict__ ptok, int* __restrict__ pos_of) {
  int token = blockIdx.x * 256 + threadIdx.x;
  if (token >= S_LEN) return;
  for (int k = 0; k < 2; ++k) {
    int e = topi[2 * token + k];
    int pos = atomicAdd(&cursor[e], 1);
    ptok[pos] = token;
    pos_of[2 * token + k] = pos;
  }
}

// ======== MoE dual GEMM body, BM=128 BN=64, 512 thr (8 waves 2Mx4N) =========
__device__ __forceinline__ void moe_gemm1_body(
    char* lds, const u16* __restrict__ H2, const u16* __restrict__ W1t,
    const u16* __restrict__ W3t, u16* __restrict__ U, const int* __restrict__ meta,
    const int* __restrict__ ptok, int tile, int n0blk) {
  if (tile >= meta[0]) return;
  u16* As = (u16*)lds;             // 128x64 = 16384 B
  u16* B1s = (u16*)(lds + 16384);  // 64x64  = 8192 B
  u16* B3s = (u16*)(lds + 24576);  // 64x64  = 8192 B
  int* toks = (int*)(lds + 32768); // 512 B
  const int e = meta[8 + tile], row0 = meta[64 + tile], rows = meta[120 + tile];
  const int n0 = n0blk * 64;
  const u16* B1 = W1t + (size_t)e * FF * DM + (size_t)n0 * 2048;
  const u16* B3 = W3t + (size_t)e * FF * DM + (size_t)n0 * 2048;
  const int t = threadIdx.x, lane = t & 63, w = t >> 6;
  const int wm = (w >> 2) * 64, wn = (w & 3) * 16;
  const int l15 = lane & 15, lg = lane >> 4;
  const int wbase = t & ~63;

  if (t < 128) toks[t] = (t < rows) ? ptok[row0 + t] : ptok[row0];
  __syncthreads();

  f32x4 aG[4], aT[4];
#pragma unroll
  for (int m = 0; m < 4; ++m) {
    aG[m] = (f32x4){0.f, 0.f, 0.f, 0.f};
    aT[m] = (f32x4){0.f, 0.f, 0.f, 0.f};
  }

  for (int k0 = 0; k0 < DM; k0 += 64) {
    __syncthreads();
#pragma unroll
    for (int i = 0; i < 2; ++i) {
      int p = i * 512 + t;
      int row = p >> 3;
      int csrc = (p & 7) ^ (row & 7);
      gload_lds16(H2 + (size_t)toks[row] * DM + k0 + csrc * 8, As + (i * 512 + wbase) * 8);
    }
    {
      int row = t >> 3;
      int csrc = (t & 7) ^ (row & 7);
      gload_lds16(B1 + (size_t)row * 2048 + k0 + csrc * 8, B1s + wbase * 8);
      gload_lds16(B3 + (size_t)row * 2048 + k0 + csrc * 8, B3s + wbase * 8);
    }
    __syncthreads();
#pragma unroll
    for (int kk = 0; kk < 2; ++kk) {
      bf16x8 af[4], b1f, b3f;
#pragma unroll
      for (int m = 0; m < 4; ++m) {
        int row = wm + m * 16 + l15;
        int byte = row * 128 + (((kk * 4 + lg) * 16) ^ ((row & 7) << 4));
        af[m] = *reinterpret_cast<const bf16x8*>((const char*)As + byte);
      }
      {
        int row = wn + l15;
        int byte = row * 128 + (((kk * 4 + lg) * 16) ^ ((row & 7) << 4));
        b1f = *reinterpret_cast<const bf16x8*>((const char*)B1s + byte);
        b3f = *reinterpret_cast<const bf16x8*>((const char*)B3s + byte);
      }
#pragma unroll
      for (int m = 0; m < 4; ++m) {
        aG[m] = mfma16(af[m], b1f, aG[m]);
        aT[m] = mfma16(af[m], b3f, aT[m]);
      }
    }
  }
#pragma unroll
  for (int m = 0; m < 4; ++m)
#pragma unroll
    for (int r = 0; r < 4; ++r) {
      int lrow = wm + m * 16 + lg * 4 + r;
      if (lrow < rows) {
        float g = aG[m][r], tt = aT[m][r];
        float u = (g / (1.f + __expf(-g))) * tt;
        U[(size_t)(row0 + lrow) * FF + n0 + wn + l15] = f2bf(u);
      }
    }
}

// ======== fat 3: moe_gemm1 BM=128 (2560) ∪ convT(w2 experts 4-7) x2 (4096) ==
__global__ __launch_bounds__(512) void fat_moe1(
    const u16* __restrict__ H2, const u16* __restrict__ W1t, const u16* __restrict__ W3t,
    u16* __restrict__ U, const int* __restrict__ meta128, const int* __restrict__ ptok,
    const float* __restrict__ w2, u16* __restrict__ w2t) {
  __shared__ alignas(16) char lds[33280];
  int bid = blockIdx.x;
  if (bid < 2560) {
    moe_gemm1_body(lds, H2, W1t, W3t, U, meta128, ptok, bid >> 6, bid & 63);
  } else {
    int cid = bid - 2560;
    convT_body512_x2(lds, w2, 4096, 2048, w2t, (cid & 15) * 2, (cid >> 4) & 63,
                     4 + (cid >> 10));
  }
}

// ======== MoE GEMM2, BM=128 BN=128, 512 thr (8 waves 2Mx4N) =================
__global__ __launch_bounds__(512) void moe_gemm2b(
    const u16* __restrict__ U, const u16* __restrict__ W2t, u16* __restrict__ Y,
    const int* __restrict__ meta128) {
  const int tile = blockIdx.x;
  if (tile >= meta128[0]) return;
  const int e = meta128[8 + tile], row0 = meta128[64 + tile], rows = meta128[120 + tile];
  const int n0 = blockIdx.y * 128;
  const u16* Bb = W2t + (size_t)e * DM * FF + (size_t)n0 * 4096;
  const int t = threadIdx.x, lane = t & 63, w = t >> 6;
  const int wm = (w >> 2) * 64, wn = (w & 3) * 32;
  const int l15 = lane & 15, lg = lane >> 4;
  const int wbase = t & ~63;

  __shared__ alignas(16) u16 As[8192];   // 128 x 64
  __shared__ alignas(16) u16 Bs[8192];   // 128 x 64

  f32x4 acc[4][2];
#pragma unroll
  for (int m = 0; m < 4; ++m)
#pragma unroll
    for (int n = 0; n < 2; ++n) acc[m][n] = (f32x4){0.f, 0.f, 0.f, 0.f};

  for (int k0 = 0; k0 < FF; k0 += 64) {
    __syncthreads();
#pragma unroll
    for (int i = 0; i < 2; ++i) {
      int p = i * 512 + t;
      int row = p >> 3;
      int csrc = (p & 7) ^ (row & 7);
      gload_lds16(U + (size_t)(row0 + row) * FF + k0 + csrc * 8, As + (i * 512 + wbase) * 8);
    }
#pragma unroll
    for (int i = 0; i < 2; ++i) {
      int p = i * 512 + t;
      int row = p >> 3;
      int csrc = (p & 7) ^ (row & 7);
      gload_lds16(Bb + (size_t)row * 4096 + k0 + csrc * 8, Bs + (i * 512 + wbase) * 8);
    }
    __syncthreads();
#pragma unroll
    for (int kk = 0; kk < 2; ++kk) {
      bf16x8 af[4], bfr[2];
#pragma unroll
      for (int m = 0; m < 4; ++m) {
        int row = wm + m * 16 + l15;
        int byte = row * 128 + (((kk * 4 + lg) * 16) ^ ((row & 7) << 4));
        af[m] = *reinterpret_cast<const bf16x8*>((const char*)As + byte);
      }
#pragma unroll
      for (int n = 0; n < 2; ++n) {
        int row = wn + n * 16 + l15;
        int byte = row * 128 + (((kk * 4 + lg) * 16) ^ ((row & 7) << 4));
        bfr[n] = *reinterpret_cast<const bf16x8*>((const char*)Bs + byte);
      }
#pragma unroll
      for (int m = 0; m < 4; ++m)
#pragma unroll
        for (int n = 0; n < 2; ++n) acc[m][n] = mfma16(af[m], bfr[n], acc[m][n]);
    }
  }
#pragma unroll
  for (int m = 0; m < 4; ++m)
#pragma unroll
    for (int n = 0; n < 2; ++n)
#pragma unroll
      for (int r = 0; r < 4; ++r) {
        int lrow = wm + m * 16 + lg * 4 + r;
        if (lrow < rows)
          Y[(size_t)(row0 + lrow) * DM + n0 + wn + n * 16 + l15] = f2bf(acc[m][n][r]);
      }
}

// ======== final =============================================================
__global__ __launch_bounds__(256) void moe_final_kernel(
    const float* __restrict__ x1, const u16* __restrict__ Y,
    const int* __restrict__ pos_of, const float* __restrict__ topw,
    const float* __restrict__ spost, float* __restrict__ xout) {
  __shared__ float sh[4];
  const int row = blockIdx.x, t = threadIdx.x;
  const int p0 = pos_of[2 * row], p1 = pos_of[2 * row + 1];
  const float w0 = topw[2 * row], w1 = topw[2 * row + 1];
  bf16x8 y0 = *reinterpret_cast<const bf16x8*>(Y + (size_t)p0 * DM + t * 8);
  bf16x8 y1 = *reinterpret_cast<const bf16x8*>(Y + (size_t)p1 * DM + t * 8);
  float mv[8];
  float ss = 0.f;
#pragma unroll
  for (int j = 0; j < 8; ++j) {
    mv[j] = w0 * bf2f((u16)y0[j]) + w1 * bf2f((u16)y1[j]);
    ss += mv[j] * mv[j];
  }
  float inv = rsqrtf(blocksum(ss, sh) * (1.f / DM) + EPSV);
  const size_t base = (size_t)row * DM + t * 8;
#pragma unroll
  for (int j = 0; j < 8; ++j)
    xout[base + j] = x1[base + j] + mv[j] * inv * spost[t * 8 + j];
}

// ======== host ==============================================================
extern "C" void kernel_launch(void* const* d_in, const int* in_sizes, int n_in,
                              void* d_out, int out_size, void* d_ws, size_t ws_size,
                              hipStream_t stream) {
  (void)in_sizes; (void)n_in; (void)out_size; (void)ws_size;
  const float* x = (const float*)d_in[0];
  const float* wq = (const float*)d_in[1];
  const float* wk = (const float*)d_in[2];
  const float* wv = (const float*)d_in[3];
  const float* wo = (const float*)d_in[4];
  const float* wrt = (const float*)d_in[5];
  const float* w1 = (const float*)d_in[6];
  const float* w3 = (const float*)d_in[7];
  const float* w2 = (const float*)d_in[8];
  const float* s_pre_mqa = (const float*)d_in[9];
  const float* s_post_mqa = (const float*)d_in[10];
  const float* s_pre_moe = (const float*)d_in[11];
  const float* s_post_moe = (const float*)d_in[12];

  float* xout = (float*)d_out;
  float* out_router = xout + (size_t)S_LEN * DM;

  char* wsp = (char*)d_ws;
  size_t off = 0;
  auto alloc = [&](size_t n) {
    char* p = wsp + off;
    off += (n + 255) & ~(size_t)255;
    return p;
  };
  u16* U = (u16*)alloc((size_t)4096 * FF * 2);
  u16* Y = (u16*)alloc((size_t)4096 * DM * 2);
  float* mqa = (float*)alloc((size_t)S_LEN * DM * 4);
  u16* h1s = (u16*)alloc((size_t)S_LEN * 4096 * 2);
  u16* attn_s = h1s;
  u16* Btq_hi = (u16*)alloc((size_t)2304 * 2048 * 2);
  u16* Btq_lo = (u16*)alloc((size_t)2304 * 2048 * 2);
  u16* Bto_hi = (u16*)alloc((size_t)2048 * 2048 * 2);
  u16* Bto_lo = (u16*)alloc((size_t)2048 * 2048 * 2);
  u16* QKV = (u16*)alloc((size_t)S_LEN * 4608 * 2);
  u16* vt = (u16*)alloc((size_t)256 * S_LEN * 2);
  float* x1 = (float*)alloc((size_t)S_LEN * DM * 4);
  u16* h2b = (u16*)alloc((size_t)S_LEN * DM * 2);
  int* topi = (int*)alloc(4096 * 4);
  float* topw = (float*)alloc(4096 * 4);
  int* pos_of = (int*)alloc(4096 * 4);
  int* ptok = (int*)alloc(4352 * 4);
  int* cnt = (int*)alloc(32 * 4);
  int* cursor = (int*)alloc(32 * 4);
  int* meta = (int*)alloc(256 * 4);
  int* meta128 = (int*)alloc(256 * 4);
  u16* w1t = (u16*)alloc((size_t)NEXP * DM * FF * 2);
  u16* w3t = (u16*)alloc((size_t)NEXP * DM * FF * 2);
  u16* w2t = (u16*)alloc((size_t)NEXP * FF * DM * 2);

  dim3 B256(256);
  dim3 B512(512);

  // pre-phase: rms_pre (2048) ∪ convsplit wq/wk/wv (1152)
  fat_pre<<<dim3(3200), B256, 0, stream>>>(x, s_pre_mqa, h1s, wq, wk, wv, Btq_hi, Btq_lo);
  // QKV gemm3 (576) ∪ convT(w1) x2-tile (8192) ∪ convsplit(wo) (1024)
  fat_qkv_conv<<<dim3(576 + 8192 + 1024), B256, 0, stream>>>(
      h1s, Btq_hi, Btq_lo, QKV, w1, w1t, wo, Bto_hi, Bto_lo);
  vtrans_kernel<<<dim3(32, 4), B256, 0, stream>>>(QKV, vt);
  // attention (512) ∪ convT(w3) x2-tile (8192)
  fat_attn_conv<<<dim3(512 + 8192), B256, 0, stream>>>(QKV, vt, attn_s, w3, w3t);
  // wo gemm3 (512) ∪ convT(w2 experts 0-3) x2-tile (4096)
  fat_wo_conv<<<dim3(512 + 4096), B256, 0, stream>>>(attn_s, Bto_hi, Bto_lo, mqa, w2, w2t);
  zero_meta_kernel<<<dim3(1), dim3(64), 0, stream>>>(cnt);
  rms_mid_router<<<dim3(S_LEN), B256, 0, stream>>>(x, mqa, s_post_mqa, s_pre_moe, wrt,
                                                   x1, h2b, out_router, topi, topw, cnt);
  build_meta_kernel<<<dim3(1), dim3(64), 0, stream>>>(cnt, cursor, meta, meta128);
  scatter_kernel<<<dim3(8), B256, 0, stream>>>(topi, cursor, ptok, pos_of);
  // moe gemm1 BM=128 (2560) ∪ convT(w2 experts 4-7) x2-tile (4096)
  fat_moe1<<<dim3(2560 + 4096), B512, 0, stream>>>(h2b, w1t, w3t, U, meta128, ptok, w2, w2t);
  // moe gemm2 BM=128 BN=128 (40x16)
  moe_gemm2b<<<dim3(40, 16), B512, 0, stream>>>(U, w2t, Y, meta128);
  moe_final_kernel<<<dim3(S_LEN), B256, 0, stream>>>(x1, Y, pos_of, topw, s_post_moe, xout);
}